// Round 6
// baseline (65875.214 us; speedup 1.0000x reference)
//
#include <hip/hip_runtime.h>
#include <hip/hip_bf16.h>
#include <cstdint>
#include <cstddef>

// ---------------------------------------------------------------------------
// 2-layer LSTM (H=1024) + additive attention + linear head, B=128 T=512 D=128
// Strategy: persistent weight-stationary kernel (weights in VGPRs as MFMA
// B-fragments), 256 WGs = 1/CU, per-group (64 WG) atomic barrier per step,
// layers software-pipelined (513 global steps). Then MFMA GEMM for attention
// scores + small softmax/context kernel.
// ---------------------------------------------------------------------------

typedef __bf16 bf16x8 __attribute__((ext_vector_type(8)));
typedef __bf16 bf16x4 __attribute__((ext_vector_type(4)));
typedef float  f32x4  __attribute__((ext_vector_type(4)));

#define BH 131072  // 128*1024 elements per h snapshot

constexpr size_t BAR_OFF  = 0;           // barrier counters/flags (4KB)
constexpr size_t SC_OFF   = 4096;        // scores f32 [128][512]      256KB
constexpr size_t PP_OFF   = 266240;      // h0 ping-pong bf16 [2][128][1024] 512KB
constexpr size_t WA_OFF   = 790528;      // Wa bf16 [1024][1024]       2MB
constexpr size_t XB_OFF   = 2887680;     // x bf16 [128][512][128]     16MB
constexpr size_t HIST_OFF = 19664896;    // h1 hist bf16 [513][128][1024]
constexpr size_t WS_NEED  = HIST_OFF + (size_t)513 * 262144;  // ~147MB

__device__ __forceinline__ float sigf(float x) { return 1.0f / (1.0f + __expf(-x)); }
__device__ __forceinline__ float tanhf_fast(float x) {
  float t = __expf(-2.0f * fabsf(x));
  float r = (1.0f - t) / (1.0f + t);
  return x >= 0.0f ? r : -r;
}
__device__ __forceinline__ f32x4 mfma16(bf16x8 a, bf16x8 b, f32x4 c) {
  return __builtin_amdgcn_mfma_f32_16x16x32_bf16(a, b, c, 0, 0, 0);
}
__device__ __forceinline__ bf16x8 ldb8(const __bf16* p) { return *(const bf16x8*)p; }
__device__ __forceinline__ bf16x8 cvt8(const float* p) {
  f32x4 a = *(const f32x4*)p;
  f32x4 b = *(const f32x4*)(p + 4);
  bf16x8 r;
  r[0] = (__bf16)a[0]; r[1] = (__bf16)a[1]; r[2] = (__bf16)a[2]; r[3] = (__bf16)a[3];
  r[4] = (__bf16)b[0]; r[5] = (__bf16)b[1]; r[6] = (__bf16)b[2]; r[7] = (__bf16)b[3];
  return r;
}
__device__ __forceinline__ void gload16(const void* g, void* lds) {
  __builtin_amdgcn_global_load_lds(
      (const __attribute__((address_space(1))) unsigned int*)g,
      (__attribute__((address_space(3))) unsigned int*)lds, 16, 0, 0);
}

// ---------------------------------------------------------------------------
// init: zero barrier/scores/pp + hist slot 0; convert Wa and x to bf16
// ---------------------------------------------------------------------------
__global__ void init_kernel(const float* __restrict__ Wa, const float* __restrict__ x,
                            char* __restrict__ ws) {
  const size_t Z1 = 790528 / 16;         // bytes [0, PP end) as 16B chunks
  const size_t Z2 = 262144 / 16;         // hist slot 0
  const size_t CW = (1024 * 1024) / 8;   // Wa chunks of 8 floats
  const size_t CX = (128 * 512 * 128) / 8;
  size_t i = (size_t)blockIdx.x * blockDim.x + threadIdx.x;
  const size_t stride = (size_t)gridDim.x * blockDim.x;
  const size_t total = Z1 + Z2 + CW + CX;
  uint4 z; z.x = z.y = z.z = z.w = 0u;
  for (; i < total; i += stride) {
    if (i < Z1) {
      ((uint4*)ws)[i] = z;
    } else if (i < Z1 + Z2) {
      ((uint4*)(ws + HIST_OFF))[i - Z1] = z;
    } else if (i < Z1 + Z2 + CW) {
      size_t c = i - Z1 - Z2;
      ((bf16x8*)(ws + WA_OFF))[c] = cvt8(Wa + c * 8);
    } else {
      size_t c = i - Z1 - Z2 - CW;
      ((bf16x8*)(ws + XB_OFF))[c] = cvt8(x + c * 8);
    }
  }
}

// ---------------------------------------------------------------------------
// persistent LSTM: 256 WGs x 512 threads, 1/CU (96KB LDS), 513 global steps
// ---------------------------------------------------------------------------
__global__ __launch_bounds__(512, 2) void lstm_persist(
    const float* __restrict__ Wih0, const float* __restrict__ Whh0,
    const float* __restrict__ bih0, const float* __restrict__ bhh0,
    const float* __restrict__ Wih1, const float* __restrict__ Whh1,
    const float* __restrict__ bih1, const float* __restrict__ bhh1,
    char* __restrict__ ws) {
  // 96KB LDS: forces 1 WG/CU; gates A at [0, 32*68), gates B at
  // [2176, 2176+32*68) (padded 68 vs 64 -> mild bank aliasing),
  // bias stash (bih+bhh, both layers, this WG's 16 h-dims) at [4352, 4480)
  __shared__ float gAll[24576];

  const int tid  = threadIdx.x;
  const int lane = tid & 63;
  const int l15  = lane & 15;
  const int l4g  = lane >> 4;
  const int wv   = __builtin_amdgcn_readfirstlane(tid >> 6);  // wave 0..7
  const int bid  = blockIdx.x;
  const int grp  = (bid & 7) >> 1;                 // batch group (2 XCDs each)
  const int hch  = ((bid >> 3) << 1) | (bid & 1);  // h-chunk 0..63
  const int bbase = grp * 32;
  const int hbase = hch * 16;

  unsigned* cnt = (unsigned*)(ws + (size_t)grp * 256);
  unsigned* rel = (unsigned*)(ws + 2048 + (size_t)grp * 256);
  __bf16* pp   = (__bf16*)(ws + PP_OFF);
  __bf16* hist = (__bf16*)(ws + HIST_OFF);
  const __bf16* xb = (const __bf16*)(ws + XB_OFF);

  // bias stash: tid<128 -> layer (tid>>6), gate ((tid>>4)&3), dim (tid&15)
  if (tid < 128) {
    const int ly = tid >> 6, gt = (tid >> 4) & 3, dd = tid & 15;
    const int gidx = gt * 1024 + hbase + dd;
    gAll[4352 + tid] = ly ? (bih1[gidx] + bhh1[gidx])
                          : (bih0[gidx] + bhh0[gidx]);
  }

  // K split: phase A (layer0) 36 k-tiles (h0:0..31, x:32..35), phase B 64
  // (h0/Wih1:0..31, h1/Whh1:32..63). Wave w owns contiguous tile ranges.
  const int kaStart = (36 * wv) >> 3;
  const int countA  = ((36 * (wv + 1)) >> 3) - kaStart;  // 4 or 5
  const int kbStart = wv * 8;

  // ---- stationary weights: load f32 once, keep bf16 fragments in VGPRs ----
  bf16x8 wA[5][4];
  bf16x8 wB[8][4];
  #pragma unroll
  for (int ki = 0; ki < 5; ++ki) {
    if (ki < countA) {
      const int kt = kaStart + ki;
      const int kk = kt * 32 + l4g * 8;
      #pragma unroll
      for (int nt = 0; nt < 4; ++nt) {  // nt == gate (i,f,g,o)
        const int row = nt * 1024 + hbase + l15;
        const float* src = (kt < 32) ? (Whh0 + (size_t)row * 1024 + kk)
                                     : (Wih0 + (size_t)row * 128 + (kk - 1024));
        wA[ki][nt] = cvt8(src);
      }
    }
  }
  #pragma unroll
  for (int ki = 0; ki < 8; ++ki) {
    const int kt = kbStart + ki;
    const int kk = kt * 32 + l4g * 8;
    #pragma unroll
    for (int nt = 0; nt < 4; ++nt) {
      const int row = nt * 1024 + hbase + l15;
      const float* src = (kt < 32) ? (Wih1 + (size_t)row * 1024 + kk)
                                   : (Whh1 + (size_t)row * 1024 + (kk - 1024));
      wB[ki][nt] = cvt8(src);
    }
  }

  float c0 = 0.0f, c1 = 0.0f;         // cell state, fp32, thread-resident
  const int eb   = tid >> 4;           // elementwise: batch-in-chunk
  const int ehd  = tid & 15;           // h-dim-in-chunk
  const int hidx = hbase + ehd;
  const int ebg  = bbase + eb;
  const f32x4 z4 = {0.0f, 0.0f, 0.0f, 0.0f};
  int patience = 1 << 17;              // latched barrier timeout

  #pragma clang loop unroll(disable)
  for (int s = 0; s <= 512; ++s) {
    for (int i = tid; i < 4352; i += 512) gAll[i] = 0.0f;
    __syncthreads();

    const __bf16* ppPrev = pp + (size_t)((s + 1) & 1) * BH;  // h0[s-1]

    if (s < 512) {  // layer 0: h0[s] from h0[s-1], x[s]
      #pragma unroll
      for (int mt = 0; mt < 2; ++mt) {
        const int mrow = bbase + mt * 16 + l15;
        const __bf16* hrow = ppPrev + (size_t)mrow * 1024;
        const __bf16* xrow = xb + (size_t)mrow * 65536 + s * 128 - 1024;
        f32x4 a0 = z4, a1 = z4, a2 = z4, a3 = z4;
        #pragma unroll
        for (int ki = 0; ki < 5; ++ki) {
          if (ki < countA) {
            const int kt = kaStart + ki;
            const int kk = kt * 32 + l4g * 8;
            const __bf16* ap = (kt < 32) ? (hrow + kk) : (xrow + kk);
            bf16x8 a = ldb8(ap);
            a0 = mfma16(a, wA[ki][0], a0);
            a1 = mfma16(a, wA[ki][1], a1);
            a2 = mfma16(a, wA[ki][2], a2);
            a3 = mfma16(a, wA[ki][3], a3);
          }
        }
        const int gm = mt * 16 + l4g * 4;
        #pragma unroll
        for (int ri = 0; ri < 4; ++ri) {
          atomicAdd(&gAll[(gm + ri) * 68 +      l15], a0[ri]);
          atomicAdd(&gAll[(gm + ri) * 68 + 16 + l15], a1[ri]);
          atomicAdd(&gAll[(gm + ri) * 68 + 32 + l15], a2[ri]);
          atomicAdd(&gAll[(gm + ri) * 68 + 48 + l15], a3[ri]);
        }
      }
    }
    if (s >= 1) {  // layer 1: h1[s-1] from h0[s-1], h1[s-2]
      const __bf16* h1base = hist + (size_t)(s - 1) * BH;
      #pragma unroll
      for (int mt = 0; mt < 2; ++mt) {
        const int mrow = bbase + mt * 16 + l15;
        const __bf16* h0row = ppPrev + (size_t)mrow * 1024;
        const __bf16* h1row = h1base + (size_t)mrow * 1024 - 1024;
        f32x4 a0 = z4, a1 = z4, a2 = z4, a3 = z4;
        #pragma unroll
        for (int ki = 0; ki < 8; ++ki) {
          const int kt = kbStart + ki;
          const int kk = kt * 32 + l4g * 8;
          const __bf16* ap = (kt < 32) ? (h0row + kk) : (h1row + kk);
          bf16x8 a = ldb8(ap);
          a0 = mfma16(a, wB[ki][0], a0);
          a1 = mfma16(a, wB[ki][1], a1);
          a2 = mfma16(a, wB[ki][2], a2);
          a3 = mfma16(a, wB[ki][3], a3);
        }
        const int gm = mt * 16 + l4g * 4;
        #pragma unroll
        for (int ri = 0; ri < 4; ++ri) {
          atomicAdd(&gAll[2176 + (gm + ri) * 68 +      l15], a0[ri]);
          atomicAdd(&gAll[2176 + (gm + ri) * 68 + 16 + l15], a1[ri]);
          atomicAdd(&gAll[2176 + (gm + ri) * 68 + 32 + l15], a2[ri]);
          atomicAdd(&gAll[2176 + (gm + ri) * 68 + 48 + l15], a3[ri]);
        }
      }
    }
    __syncthreads();

    // ---- elementwise cells (fp32), one thread per (batch, h-dim) ----
    if (s < 512) {
      float gi = gAll[eb * 68 +      ehd] + gAll[4352 +      ehd];
      float gf = gAll[eb * 68 + 16 + ehd] + gAll[4352 + 16 + ehd];
      float gg = gAll[eb * 68 + 32 + ehd] + gAll[4352 + 32 + ehd];
      float go = gAll[eb * 68 + 48 + ehd] + gAll[4352 + 48 + ehd];
      c0 = sigf(gf) * c0 + sigf(gi) * tanhf_fast(gg);
      float hv = sigf(go) * tanhf_fast(c0);
      pp[(size_t)(s & 1) * BH + (size_t)ebg * 1024 + hidx] = (__bf16)hv;
    }
    if (s >= 1) {
      float gi = gAll[2176 + eb * 68 +      ehd] + gAll[4416 +      ehd];
      float gf = gAll[2176 + eb * 68 + 16 + ehd] + gAll[4416 + 16 + ehd];
      float gg = gAll[2176 + eb * 68 + 32 + ehd] + gAll[4416 + 32 + ehd];
      float go = gAll[2176 + eb * 68 + 48 + ehd] + gAll[4416 + 48 + ehd];
      c1 = sigf(gf) * c1 + sigf(gi) * tanhf_fast(gg);
      float hv = sigf(go) * tanhf_fast(c1);
      hist[(size_t)s * BH + (size_t)ebg * 1024 + hidx] = (__bf16)hv;
    }

    // ---- per-group barrier (64 WGs, monotone counter + epoch flag) ----
    __threadfence();
    __syncthreads();
    if (tid == 0) {
      unsigned old = atomicAdd(cnt, 1u);
      if (old == (unsigned)(64 * (s + 1) - 1)) {
        __hip_atomic_store(rel, (unsigned)(s + 1), __ATOMIC_RELEASE, __HIP_MEMORY_SCOPE_AGENT);
      }
      int gd = 0;
      while (__hip_atomic_load(rel, __ATOMIC_ACQUIRE, __HIP_MEMORY_SCOPE_AGENT) <
             (unsigned)(s + 1)) {
        __builtin_amdgcn_s_sleep(1);
        if (++gd > patience) { patience = 64; break; }  // fail fast, visibly
      }
    }
    __syncthreads();
    __threadfence();
  }
}

// ---------------------------------------------------------------------------
// scores: S[b][t] = v . tanh(Wa h1[b][t] + ba)  via 128x128-tile MFMA GEMM
// grid (512 t-tiles, 8 n-tiles), fused tanh*v row-reduce + atomicAdd
// ---------------------------------------------------------------------------
__global__ void score_gemm(char* __restrict__ ws, const float* __restrict__ ba,
                           const float* __restrict__ v) {
  __shared__ __bf16 As[128 * 64];
  __shared__ __bf16 Bs[128 * 64];
  __shared__ float rowpart[128 * 2];

  const int tid  = threadIdx.x;
  const int lane = tid & 63;
  const int l15  = lane & 15;
  const int l4g  = lane >> 4;
  const int wv   = __builtin_amdgcn_readfirstlane(tid >> 6);  // 0..3
  const int mq   = wv >> 1;
  const int nq   = wv & 1;
  const int tt    = blockIdx.x;   // time index (tile of 128 batch rows)
  const int nTile = blockIdx.y;   // 128 gate cols

  const __bf16* Ag = (const __bf16*)(ws + HIST_OFF) + (size_t)(tt + 1) * BH;
  const __bf16* Bg = (const __bf16*)(ws + WA_OFF) + (size_t)nTile * 128 * 1024;
  float* scores = (float*)(ws + SC_OFF);

  const f32x4 z4 = {0.0f, 0.0f, 0.0f, 0.0f};
  f32x4 acc[4][4];
  #pragma unroll
  for (int i = 0; i < 4; ++i)
    #pragma unroll
    for (int j = 0; j < 4; ++j) acc[i][j] = z4;

  const int srow = lane >> 3;
  const int scol = (lane & 7) * 8;

  for (int kk = 0; kk < 16; ++kk) {
    #pragma unroll
    for (int i = 0; i < 4; ++i) {
      const int rowblock = wv * 32 + i * 8;
      const int row = rowblock + srow;
      gload16(Ag + (size_t)row * 1024 + kk * 64 + scol, (void*)&As[rowblock * 64]);
      gload16(Bg + (size_t)row * 1024 + kk * 64 + scol, (void*)&Bs[rowblock * 64]);
    }
    __syncthreads();
    #pragma unroll
    for (int kt = 0; kt < 2; ++kt) {
      bf16x8 aF[4], bF[4];
      #pragma unroll
      for (int mt = 0; mt < 4; ++mt)
        aF[mt] = *(const bf16x8*)&As[(mq * 64 + mt * 16 + l15) * 64 + kt * 32 + l4g * 8];
      #pragma unroll
      for (int nt = 0; nt < 4; ++nt)
        bF[nt] = *(const bf16x8*)&Bs[(nq * 64 + nt * 16 + l15) * 64 + kt * 32 + l4g * 8];
      #pragma unroll
      for (int mt = 0; mt < 4; ++mt)
        #pragma unroll
        for (int nt = 0; nt < 4; ++nt)
          acc[mt][nt] = mfma16(aF[mt], bF[nt], acc[mt][nt]);
    }
    __syncthreads();
  }

  // epilogue: tanh(acc + ba)*v, reduce over this WG's 128 cols
  float bav[4], vvv[4];
  #pragma unroll
  for (int nt = 0; nt < 4; ++nt) {
    const int col = nTile * 128 + nq * 64 + nt * 16 + l15;
    bav[nt] = ba[col];
    vvv[nt] = v[col];
  }
  #pragma unroll
  for (int mt = 0; mt < 4; ++mt) {
    #pragma unroll
    for (int ri = 0; ri < 4; ++ri) {
      float ssum = 0.0f;
      #pragma unroll
      for (int nt = 0; nt < 4; ++nt)
        ssum += tanhf_fast(acc[mt][nt][ri] + bav[nt]) * vvv[nt];
      #pragma unroll
      for (int off = 1; off < 16; off <<= 1) ssum += __shfl_xor(ssum, off, 16);
      if (l15 == 0) rowpart[(mq * 64 + mt * 16 + l4g * 4 + ri) * 2 + nq] = ssum;
    }
  }
  __syncthreads();
  if (tid < 128) {
    float val = rowpart[tid * 2] + rowpart[tid * 2 + 1];
    atomicAdd(scores + (size_t)tid * 512 + tt, val);  // scores[b][t]
  }
}

// ---------------------------------------------------------------------------
// softmax over t + context + output head. 1 block per batch row.
// ---------------------------------------------------------------------------
__global__ void attn_final(const char* __restrict__ ws, const float* __restrict__ Wf,
                           const float* __restrict__ bfv, float* __restrict__ out) {
  __shared__ float wbuf[512];
  __shared__ float red[8];
  const int b = blockIdx.x;
  const int tid = threadIdx.x;  // 256
  const float* scores = (const float*)(ws + SC_OFF) + (size_t)b * 512;
  const __bf16* hist = (const __bf16*)(ws + HIST_OFF);

  float m = -1e30f;
  for (int t = tid; t < 512; t += 256) m = fmaxf(m, scores[t]);
  #pragma unroll
  for (int off = 32; off > 0; off >>= 1) m = fmaxf(m, __shfl_xor(m, off));
  if ((tid & 63) == 0) red[tid >> 6] = m;
  __syncthreads();
  m = fmaxf(fmaxf(red[0], red[1]), fmaxf(red[2], red[3]));

  float sum = 0.0f;
  for (int t = tid; t < 512; t += 256) {
    float e = __expf(scores[t] - m);
    wbuf[t] = e;
    sum += e;
  }
  #pragma unroll
  for (int off = 32; off > 0; off >>= 1) sum += __shfl_xor(sum, off);
  if ((tid & 63) == 0) red[4 + (tid >> 6)] = sum;
  __syncthreads();
  sum = red[4] + red[5] + red[6] + red[7];
  const float inv = 1.0f / sum;

  float a0 = 0, a1 = 0, a2 = 0, a3 = 0;
  const int d0 = tid * 4;
  const __bf16* hb = hist + BH + (size_t)b * 1024 + d0;
  for (int t = 0; t < 512; ++t) {
    const float wt = wbuf[t];
    bf16x4 hv = *(const bf16x4*)(hb + (size_t)t * BH);
    a0 += wt * (float)hv[0];
    a1 += wt * (float)hv[1];
    a2 += wt * (float)hv[2];
    a3 += wt * (float)hv[3];
  }
  float local = (a0 * Wf[d0] + a1 * Wf[d0 + 1] + a2 * Wf[d0 + 2] + a3 * Wf[d0 + 3]) * inv;
  #pragma unroll
  for (int off = 32; off > 0; off >>= 1) local += __shfl_xor(local, off);
  __syncthreads();
  if ((tid & 63) == 0) red[tid >> 6] = local;
  __syncthreads();
  if (tid == 0) out[b] = red[0] + red[1] + red[2] + red[3] + bfv[0];
}

// ---------------------------------------------------------------------------
extern "C" void kernel_launch(void* const* d_in, const int* in_sizes, int n_in,
                              void* d_out, int out_size, void* d_ws, size_t ws_size,
                              hipStream_t stream) {
  const float* x    = (const float*)d_in[0];
  const float* Wih0 = (const float*)d_in[1];
  const float* Whh0 = (const float*)d_in[2];
  const float* bih0 = (const float*)d_in[3];
  const float* bhh0 = (const float*)d_in[4];
  const float* Wih1 = (const float*)d_in[5];
  const float* Whh1 = (const float*)d_in[6];
  const float* bih1 = (const float*)d_in[7];
  const float* bhh1 = (const float*)d_in[8];
  const float* Wa   = (const float*)d_in[9];
  const float* ba   = (const float*)d_in[10];
  const float* v    = (const float*)d_in[11];
  const float* Wf   = (const float*)d_in[12];
  const float* bfv  = (const float*)d_in[13];
  char* ws = (char*)d_ws;
  float* out = (float*)d_out;
  (void)in_sizes; (void)n_in; (void)out_size;

  if (ws_size < WS_NEED) return;  // insufficient workspace -> visible absmax fail

  init_kernel<<<2048, 256, 0, stream>>>(Wa, x, ws);
  lstm_persist<<<256, 512, 0, stream>>>(Wih0, Whh0, bih0, bhh0,
                                        Wih1, Whh1, bih1, bhh1, ws);
  score_gemm<<<dim3(512, 8), 256, 0, stream>>>(ws, ba, v);
  attn_final<<<128, 256, 0, stream>>>(ws, Wf, bfv, out);
}

// Round 7
// 48188.443 us; speedup vs baseline: 1.3670x; 1.3670x over previous
//
#include <hip/hip_runtime.h>
#include <hip/hip_bf16.h>
#include <cstdint>
#include <cstddef>

// ---------------------------------------------------------------------------
// 2-layer LSTM (H=1024) + additive attention + linear head, B=128 T=512 D=128
// r6 fix: round-5 run proved weight spill (VGPR_Count=128 vs 208 needed) ->
// re-partition to 2 batch groups x 128 h-chunks so weights = 104 VGPR/lane,
// per-wave LDS partial slices (no atomics, no zeroing), 3-level tree barrier.
// ---------------------------------------------------------------------------

typedef __bf16 bf16x8 __attribute__((ext_vector_type(8)));
typedef __bf16 bf16x4 __attribute__((ext_vector_type(4)));
typedef float  f32x4  __attribute__((ext_vector_type(4)));

#define BH 131072  // 128*1024 elements per h snapshot

constexpr size_t BAR_OFF  = 0;           // barrier counters (4KB)
constexpr size_t SC_OFF   = 4096;        // scores f32 [128][512]      256KB
constexpr size_t PP_OFF   = 266240;      // h0 ping-pong bf16 [2][128][1024] 512KB
constexpr size_t WA_OFF   = 790528;      // Wa bf16 [1024][1024]       2MB
constexpr size_t XB_OFF   = 2887680;     // x bf16 [128][512][128]     16MB
constexpr size_t HIST_OFF = 19664896;    // h1 hist bf16 [513][128][1024]
constexpr size_t WS_NEED  = HIST_OFF + (size_t)513 * 262144;  // ~147MB

__device__ __forceinline__ float sigf(float x) { return 1.0f / (1.0f + __expf(-x)); }
__device__ __forceinline__ float tanhf_fast(float x) {
  float t = __expf(-2.0f * fabsf(x));
  float r = (1.0f - t) / (1.0f + t);
  return x >= 0.0f ? r : -r;
}
__device__ __forceinline__ f32x4 mfma16(bf16x8 a, bf16x8 b, f32x4 c) {
  return __builtin_amdgcn_mfma_f32_16x16x32_bf16(a, b, c, 0, 0, 0);
}
__device__ __forceinline__ bf16x8 ldb8(const __bf16* p) { return *(const bf16x8*)p; }
__device__ __forceinline__ bf16x8 cvt8(const float* p) {
  f32x4 a = *(const f32x4*)p;
  f32x4 b = *(const f32x4*)(p + 4);
  bf16x8 r;
  r[0] = (__bf16)a[0]; r[1] = (__bf16)a[1]; r[2] = (__bf16)a[2]; r[3] = (__bf16)a[3];
  r[4] = (__bf16)b[0]; r[5] = (__bf16)b[1]; r[6] = (__bf16)b[2]; r[7] = (__bf16)b[3];
  return r;
}
__device__ __forceinline__ void gload16(const void* g, void* lds) {
  __builtin_amdgcn_global_load_lds(
      (const __attribute__((address_space(1))) unsigned int*)g,
      (__attribute__((address_space(3))) unsigned int*)lds, 16, 0, 0);
}

// ---------------------------------------------------------------------------
// init: zero barrier/scores/pp + hist slot 0; convert Wa and x to bf16
// ---------------------------------------------------------------------------
__global__ void init_kernel(const float* __restrict__ Wa, const float* __restrict__ x,
                            char* __restrict__ ws) {
  const size_t Z1 = 790528 / 16;         // bytes [0, PP end) as 16B chunks
  const size_t Z2 = 262144 / 16;         // hist slot 0
  const size_t CW = (1024 * 1024) / 8;   // Wa chunks of 8 floats
  const size_t CX = (128 * 512 * 128) / 8;
  size_t i = (size_t)blockIdx.x * blockDim.x + threadIdx.x;
  const size_t stride = (size_t)gridDim.x * blockDim.x;
  const size_t total = Z1 + Z2 + CW + CX;
  uint4 z; z.x = z.y = z.z = z.w = 0u;
  for (; i < total; i += stride) {
    if (i < Z1) {
      ((uint4*)ws)[i] = z;
    } else if (i < Z1 + Z2) {
      ((uint4*)(ws + HIST_OFF))[i - Z1] = z;
    } else if (i < Z1 + Z2 + CW) {
      size_t c = i - Z1 - Z2;
      ((bf16x8*)(ws + WA_OFF))[c] = cvt8(Wa + c * 8);
    } else {
      size_t c = i - Z1 - Z2 - CW;
      ((bf16x8*)(ws + XB_OFF))[c] = cvt8(x + c * 8);
    }
  }
}

// ---------------------------------------------------------------------------
// persistent LSTM: 256 WGs x 512 threads, 1 WG/CU (135KB LDS), 513 steps.
// WG = (batch group grp in {0,1}: 64 rows) x (h-chunk hch in 0..127: 8 dims).
// Per WG: M=64 (4 mtiles), N=32 gate-rows (2 ntiles: gates {i,f} and {g,o}),
// K split across 8 waves. Weights VGPR-resident: wA[<=5][2]+wB[8][2] = 104 v.
// ---------------------------------------------------------------------------
__global__ __launch_bounds__(512, 2) void lstm_persist(
    const float* __restrict__ Wih0, const float* __restrict__ Whh0,
    const float* __restrict__ bih0, const float* __restrict__ bhh0,
    const float* __restrict__ Wih1, const float* __restrict__ Whh1,
    const float* __restrict__ bih1, const float* __restrict__ bhh1,
    char* __restrict__ ws) {
  // LDS (floats): phase-A slices [8 waves][64 rows][33] at 0,
  // phase-B slices at 16896, bias stash [2][4][8] at 33792. 135,424 B total.
  __shared__ float gAll[33856];

  const int tid  = threadIdx.x;
  const int lane = tid & 63;
  const int l15  = lane & 15;
  const int l4g  = lane >> 4;
  const int wv   = __builtin_amdgcn_readfirstlane(tid >> 6);  // wave 0..7
  const int bid  = blockIdx.x;
  const int grp  = (bid >> 2) & 1;                    // batch group (XCDs 0-3 / 4-7)
  const int hch  = ((bid >> 3) << 2) | (bid & 3);     // h-chunk 0..127
  const int bbase = grp * 64;
  const int hbase = hch * 8;

  // tree barrier lines (64B spacing, within 4KB BAR area, zeroed by init):
  char* barb = ws + (size_t)grp * 2048;
  unsigned* cell = (unsigned*)(barb + (hch >> 3) * 64);    // 16 cells of 8 WGs
  unsigned* mid  = (unsigned*)(barb + 1024 + (hch >> 6) * 64);  // 2 mids of 8 cells
  unsigned* root = (unsigned*)(barb + 1152);               // 1 root of 2 mids
  unsigned* rel  = (unsigned*)(barb + 1536);               // release flag

  __bf16* pp   = (__bf16*)(ws + PP_OFF);
  __bf16* hist = (__bf16*)(ws + HIST_OFF);
  const __bf16* xb = (const __bf16*)(ws + XB_OFF);

  // bias stash: tid<64 -> layer (tid>>5), gate ((tid>>3)&3), dim (tid&7)
  if (tid < 64) {
    const int ly = tid >> 5, gt = (tid >> 3) & 3, dd = tid & 7;
    const int gidx = gt * 1024 + hbase + dd;
    gAll[33792 + tid] = ly ? (bih1[gidx] + bhh1[gidx])
                           : (bih0[gidx] + bhh0[gidx]);
  }

  // K split: phase A (layer0) 36 ktiles (h0:0..31, x:32..35); phase B 64
  // (h0/Wih1:0..31, h1/Whh1:32..63). Wave w owns contiguous ranges.
  const int kaStart = (36 * wv) >> 3;
  const int countA  = ((36 * (wv + 1)) >> 3) - kaStart;  // 4 or 5
  const int kbStart = wv * 8;

  // weight row for (ntile, l15): gates {i,f} in ntile0, {g,o} in ntile1
  const int wrow0 = ((l15 >> 3)) * 1024 + hbase + (l15 & 7);       // ntile 0
  const int wrow1 = (2 + (l15 >> 3)) * 1024 + hbase + (l15 & 7);   // ntile 1

  // ---- stationary weights: bf16 MFMA B-fragments in VGPRs (104 VGPRs) ----
  bf16x8 wA[5][2];
  bf16x8 wB[8][2];
  #pragma unroll
  for (int ki = 0; ki < 5; ++ki) {
    if (ki < countA) {
      const int kt = kaStart + ki;
      const int kk = kt * 32 + l4g * 8;
      if (kt < 32) {
        wA[ki][0] = cvt8(Whh0 + (size_t)wrow0 * 1024 + kk);
        wA[ki][1] = cvt8(Whh0 + (size_t)wrow1 * 1024 + kk);
      } else {
        wA[ki][0] = cvt8(Wih0 + (size_t)wrow0 * 128 + (kk - 1024));
        wA[ki][1] = cvt8(Wih0 + (size_t)wrow1 * 128 + (kk - 1024));
      }
    }
  }
  #pragma unroll
  for (int ki = 0; ki < 8; ++ki) {
    const int kt = kbStart + ki;
    const int kk = kt * 32 + l4g * 8;
    if (kt < 32) {
      wB[ki][0] = cvt8(Wih1 + (size_t)wrow0 * 1024 + kk);
      wB[ki][1] = cvt8(Wih1 + (size_t)wrow1 * 1024 + kk);
    } else {
      wB[ki][0] = cvt8(Whh1 + (size_t)wrow0 * 1024 + (kk - 1024));
      wB[ki][1] = cvt8(Whh1 + (size_t)wrow1 * 1024 + (kk - 1024));
    }
  }

  float c0 = 0.0f, c1 = 0.0f;          // cell state, fp32, thread-resident
  const int eb  = tid >> 3;            // elementwise: batch-in-group 0..63
  const int ehd = tid & 7;             // h-dim-in-chunk 0..7
  const int hidx = hbase + ehd;
  const int ebg  = bbase + eb;
  const int wbase = wv * 2112;         // this wave's slice base (64*33)
  const f32x4 z4 = {0.0f, 0.0f, 0.0f, 0.0f};
  int patience = 1 << 17;              // latched barrier timeout

  #pragma clang loop unroll(disable)
  for (int s = 0; s <= 512; ++s) {
    const __bf16* ppPrev = pp + (size_t)((s + 1) & 1) * BH;  // h0[s-1]

    if (s < 512) {  // layer 0: h0[s] = f(h0[s-1], x[s])
      #pragma unroll
      for (int mt = 0; mt < 4; ++mt) {
        const int mrow = bbase + mt * 16 + l15;
        const __bf16* hrow = ppPrev + (size_t)mrow * 1024;
        const __bf16* xrow = xb + (size_t)mrow * 65536 + s * 128 - 1024;
        f32x4 a0 = z4, a1 = z4;
        #pragma unroll
        for (int ki = 0; ki < 5; ++ki) {
          if (ki < countA) {
            const int kt = kaStart + ki;
            const int kk = kt * 32 + l4g * 8;
            bf16x8 a = ldb8((kt < 32) ? (hrow + kk) : (xrow + kk));
            a0 = mfma16(a, wA[ki][0], a0);
            a1 = mfma16(a, wA[ki][1], a1);
          }
        }
        const int gbase = wbase + (mt * 16 + l4g * 4) * 33 + l15;
        #pragma unroll
        for (int ri = 0; ri < 4; ++ri) {
          gAll[gbase + ri * 33]      = a0[ri];
          gAll[gbase + ri * 33 + 16] = a1[ri];
        }
      }
    }
    if (s >= 1) {  // layer 1: h1[s-1] = f(h0[s-1], h1[s-2])
      const __bf16* h1base = hist + (size_t)(s - 1) * BH;
      #pragma unroll
      for (int mt = 0; mt < 4; ++mt) {
        const int mrow = bbase + mt * 16 + l15;
        const __bf16* h0row = ppPrev + (size_t)mrow * 1024;
        const __bf16* h1row = h1base + (size_t)mrow * 1024 - 1024;
        f32x4 b0 = z4, b1 = z4;
        #pragma unroll
        for (int ki = 0; ki < 8; ++ki) {
          const int kt = kbStart + ki;
          const int kk = kt * 32 + l4g * 8;
          bf16x8 a = ldb8((kt < 32) ? (h0row + kk) : (h1row + kk));
          b0 = mfma16(a, wB[ki][0], b0);
          b1 = mfma16(a, wB[ki][1], b1);
        }
        const int gbase = 16896 + wbase + (mt * 16 + l4g * 4) * 33 + l15;
        #pragma unroll
        for (int ri = 0; ri < 4; ++ri) {
          gAll[gbase + ri * 33]      = b0[ri];
          gAll[gbase + ri * 33 + 16] = b1[ri];
        }
      }
    }
    __syncthreads();

    // ---- elementwise cells (fp32): thread = (batch eb, dim ehd) ----
    if (s < 512) {
      const int rb = eb * 33 + ehd;
      float gi = gAll[33792 + ehd], gf = gAll[33800 + ehd];
      float gg = gAll[33808 + ehd], go = gAll[33816 + ehd];
      #pragma unroll
      for (int w = 0; w < 8; ++w) {
        const int b = w * 2112 + rb;
        gi += gAll[b]; gf += gAll[b + 8]; gg += gAll[b + 16]; go += gAll[b + 24];
      }
      c0 = sigf(gf) * c0 + sigf(gi) * tanhf_fast(gg);
      float hv = sigf(go) * tanhf_fast(c0);
      pp[(size_t)(s & 1) * BH + (size_t)ebg * 1024 + hidx] = (__bf16)hv;
    }
    if (s >= 1) {
      const int rb = 16896 + eb * 33 + ehd;
      float gi = gAll[33824 + ehd], gf = gAll[33832 + ehd];
      float gg = gAll[33840 + ehd], go = gAll[33848 + ehd];
      #pragma unroll
      for (int w = 0; w < 8; ++w) {
        const int b = w * 2112 + rb;
        gi += gAll[b]; gf += gAll[b + 8]; gg += gAll[b + 16]; go += gAll[b + 24];
      }
      c1 = sigf(gf) * c1 + sigf(gi) * tanhf_fast(gg);
      float hv = sigf(go) * tanhf_fast(c1);
      hist[(size_t)s * BH + (size_t)ebg * 1024 + hidx] = (__bf16)hv;
    }

    // ---- per-group tree barrier (128 WGs: 16 cells x8 -> 2 mids x8 -> root x2)
    __threadfence();
    __syncthreads();
    if (tid == 0) {
      const unsigned tgt = (unsigned)(s + 1);
      if (atomicAdd(cell, 1u) == 8u * tgt - 1u) {
        if (atomicAdd(mid, 1u) == 8u * tgt - 1u) {
          if (atomicAdd(root, 1u) == 2u * tgt - 1u) {
            __hip_atomic_store(rel, tgt, __ATOMIC_RELEASE, __HIP_MEMORY_SCOPE_AGENT);
          }
        }
      }
      int gd = 0;
      while (__hip_atomic_load(rel, __ATOMIC_ACQUIRE, __HIP_MEMORY_SCOPE_AGENT) < tgt) {
        __builtin_amdgcn_s_sleep(2);
        if (++gd > patience) { patience = 64; break; }  // fail fast, visibly
      }
    }
    __syncthreads();
    __threadfence();
  }
}

// ---------------------------------------------------------------------------
// scores: S[b][t] = v . tanh(Wa h1[b][t] + ba)  via 128x128-tile MFMA GEMM
// grid (512 t-tiles, 8 n-tiles), fused tanh*v row-reduce + atomicAdd
// ---------------------------------------------------------------------------
__global__ void score_gemm(char* __restrict__ ws, const float* __restrict__ ba,
                           const float* __restrict__ v) {
  __shared__ __bf16 As[128 * 64];
  __shared__ __bf16 Bs[128 * 64];
  __shared__ float rowpart[128 * 2];

  const int tid  = threadIdx.x;
  const int lane = tid & 63;
  const int l15  = lane & 15;
  const int l4g  = lane >> 4;
  const int wv   = __builtin_amdgcn_readfirstlane(tid >> 6);  // 0..3
  const int mq   = wv >> 1;
  const int nq   = wv & 1;
  const int tt    = blockIdx.x;   // time index (tile of 128 batch rows)
  const int nTile = blockIdx.y;   // 128 gate cols

  const __bf16* Ag = (const __bf16*)(ws + HIST_OFF) + (size_t)(tt + 1) * BH;
  const __bf16* Bg = (const __bf16*)(ws + WA_OFF) + (size_t)nTile * 128 * 1024;
  float* scores = (float*)(ws + SC_OFF);

  const f32x4 z4 = {0.0f, 0.0f, 0.0f, 0.0f};
  f32x4 acc[4][4];
  #pragma unroll
  for (int i = 0; i < 4; ++i)
    #pragma unroll
    for (int j = 0; j < 4; ++j) acc[i][j] = z4;

  const int srow = lane >> 3;
  const int scol = (lane & 7) * 8;

  for (int kk = 0; kk < 16; ++kk) {
    #pragma unroll
    for (int i = 0; i < 4; ++i) {
      const int rowblock = wv * 32 + i * 8;
      const int row = rowblock + srow;
      gload16(Ag + (size_t)row * 1024 + kk * 64 + scol, (void*)&As[rowblock * 64]);
      gload16(Bg + (size_t)row * 1024 + kk * 64 + scol, (void*)&Bs[rowblock * 64]);
    }
    __syncthreads();
    #pragma unroll
    for (int kt = 0; kt < 2; ++kt) {
      bf16x8 aF[4], bF[4];
      #pragma unroll
      for (int mt = 0; mt < 4; ++mt)
        aF[mt] = *(const bf16x8*)&As[(mq * 64 + mt * 16 + l15) * 64 + kt * 32 + l4g * 8];
      #pragma unroll
      for (int nt = 0; nt < 4; ++nt)
        bF[nt] = *(const bf16x8*)&Bs[(nq * 64 + nt * 16 + l15) * 64 + kt * 32 + l4g * 8];
      #pragma unroll
      for (int mt = 0; mt < 4; ++mt)
        #pragma unroll
        for (int nt = 0; nt < 4; ++nt)
          acc[mt][nt] = mfma16(aF[mt], bF[nt], acc[mt][nt]);
    }
    __syncthreads();
  }

  // epilogue: tanh(acc + ba)*v, reduce over this WG's 128 cols
  float bav[4], vvv[4];
  #pragma unroll
  for (int nt = 0; nt < 4; ++nt) {
    const int col = nTile * 128 + nq * 64 + nt * 16 + l15;
    bav[nt] = ba[col];
    vvv[nt] = v[col];
  }
  #pragma unroll
  for (int mt = 0; mt < 4; ++mt) {
    #pragma unroll
    for (int ri = 0; ri < 4; ++ri) {
      float ssum = 0.0f;
      #pragma unroll
      for (int nt = 0; nt < 4; ++nt)
        ssum += tanhf_fast(acc[mt][nt][ri] + bav[nt]) * vvv[nt];
      #pragma unroll
      for (int off = 1; off < 16; off <<= 1) ssum += __shfl_xor(ssum, off, 16);
      if (l15 == 0) rowpart[(mq * 64 + mt * 16 + l4g * 4 + ri) * 2 + nq] = ssum;
    }
  }
  __syncthreads();
  if (tid < 128) {
    float val = rowpart[tid * 2] + rowpart[tid * 2 + 1];
    atomicAdd(scores + (size_t)tid * 512 + tt, val);  // scores[b][t]
  }
}

// ---------------------------------------------------------------------------
// softmax over t + context + output head. 1 block per batch row.
// ---------------------------------------------------------------------------
__global__ void attn_final(const char* __restrict__ ws, const float* __restrict__ Wf,
                           const float* __restrict__ bfv, float* __restrict__ out) {
  __shared__ float wbuf[512];
  __shared__ float red[8];
  const int b = blockIdx.x;
  const int tid = threadIdx.x;  // 256
  const float* scores = (const float*)(ws + SC_OFF) + (size_t)b * 512;
  const __bf16* hist = (const __bf16*)(ws + HIST_OFF);

  float m = -1e30f;
  for (int t = tid; t < 512; t += 256) m = fmaxf(m, scores[t]);
  #pragma unroll
  for (int off = 32; off > 0; off >>= 1) m = fmaxf(m, __shfl_xor(m, off));
  if ((tid & 63) == 0) red[tid >> 6] = m;
  __syncthreads();
  m = fmaxf(fmaxf(red[0], red[1]), fmaxf(red[2], red[3]));

  float sum = 0.0f;
  for (int t = tid; t < 512; t += 256) {
    float e = __expf(scores[t] - m);
    wbuf[t] = e;
    sum += e;
  }
  #pragma unroll
  for (int off = 32; off > 0; off >>= 1) sum += __shfl_xor(sum, off);
  if ((tid & 63) == 0) red[4 + (tid >> 6)] = sum;
  __syncthreads();
  sum = red[4] + red[5] + red[6] + red[7];
  const float inv = 1.0f / sum;

  float a0 = 0, a1 = 0, a2 = 0, a3 = 0;
  const int d0 = tid * 4;
  const __bf16* hb = hist + BH + (size_t)b * 1024 + d0;
  for (int t = 0; t < 512; ++t) {
    const float wt = wbuf[t];
    bf16x4 hv = *(const bf16x4*)(hb + (size_t)t * BH);
    a0 += wt * (float)hv[0];
    a1 += wt * (float)hv[1];
    a2 += wt * (float)hv[2];
    a3 += wt * (float)hv[3];
  }
  float local = (a0 * Wf[d0] + a1 * Wf[d0 + 1] + a2 * Wf[d0 + 2] + a3 * Wf[d0 + 3]) * inv;
  #pragma unroll
  for (int off = 32; off > 0; off >>= 1) local += __shfl_xor(local, off);
  __syncthreads();
  if ((tid & 63) == 0) red[tid >> 6] = local;
  __syncthreads();
  if (tid == 0) out[b] = red[0] + red[1] + red[2] + red[3] + bfv[0];
}

// ---------------------------------------------------------------------------
extern "C" void kernel_launch(void* const* d_in, const int* in_sizes, int n_in,
                              void* d_out, int out_size, void* d_ws, size_t ws_size,
                              hipStream_t stream) {
  const float* x    = (const float*)d_in[0];
  const float* Wih0 = (const float*)d_in[1];
  const float* Whh0 = (const float*)d_in[2];
  const float* bih0 = (const float*)d_in[3];
  const float* bhh0 = (const float*)d_in[4];
  const float* Wih1 = (const float*)d_in[5];
  const float* Whh1 = (const float*)d_in[6];
  const float* bih1 = (const float*)d_in[7];
  const float* bhh1 = (const float*)d_in[8];
  const float* Wa   = (const float*)d_in[9];
  const float* ba   = (const float*)d_in[10];
  const float* v    = (const float*)d_in[11];
  const float* Wf   = (const float*)d_in[12];
  const float* bfv  = (const float*)d_in[13];
  char* ws = (char*)d_ws;
  float* out = (float*)d_out;
  (void)in_sizes; (void)n_in; (void)out_size;

  if (ws_size < WS_NEED) return;  // insufficient workspace -> visible absmax fail

  init_kernel<<<2048, 256, 0, stream>>>(Wa, x, ws);
  lstm_persist<<<256, 512, 0, stream>>>(Wih0, Whh0, bih0, bhh0,
                                        Wih1, Whh1, bih1, bhh1, ws);
  score_gemm<<<dim3(512, 8), 256, 0, stream>>>(ws, ba, v);
  attn_final<<<128, 256, 0, stream>>>(ws, Wf, bfv, out);
}